// Round 12
// baseline (28.801 us; speedup 1.0000x reference)
//
#include <hip/hip_runtime.h>
#include <hip/hip_bf16.h>

// Problem constants: B=16, NTX=1, S=4, OFDM=14, FFT=1024, NRX=4, NRXA=1, T=16.
// precoding_ind = arange(4) -> identity selection (folded into indexing).
#define NB    16
#define NS    4
#define NT    16
#define NOFDM 14
#define NFFT  1024
#define SITE  (NOFDM * NFFT)          // 14336 sites per b
#define NSITES (NB * SITE)            // 229376 sites total
#define TPW   4                       // t's per wave (NT / 4 waves)

// RNE float -> bf16 bits (fallback path only)
__device__ __forceinline__ unsigned short bf16_bits(float f) {
    unsigned int u = __float_as_uint(f);
    return (unsigned short)((u + 0x7FFFu + ((u >> 16) & 1u)) >> 16);
}

template <int MODE>   // 0: f32 real-part only (out_size=3670016); 1: bf16 interleaved pairs
__global__ __launch_bounds__(256, 3)   // 3 blocks/CU (LDS-capped) -> VGPR cap ~170
void zf_precoder_kernel(
    const float* __restrict__ xr, const float* __restrict__ xi,
    const float* __restrict__ hr, const float* __restrict__ hi,
    void* __restrict__ out_raw)
{
    // LDS: H tile staged so the epilogue reads LDS (kills the compiler's
    // global-load rematerialization = 117 MB/dispatch of extra fabric traffic).
    __shared__ float ldsH[4][NS * TPW][2][64];   // [wave][s*4+tt][re/im][lane] = 32 KB
    __shared__ float ldsA[4][16][64];            // partial-A exchange          = 16 KB

    const int tid  = threadIdx.x;
    const int w    = tid >> 6;                    // wave 0..3 -> t range [4w, 4w+4)
    const int l    = tid & 63;                    // lane -> site within block
    const int site = blockIdx.x * 64 + l;
    const int b    = site / SITE;
    const int rem  = site - b * SITE;             // ofdm*NFFT + fft
    const int t0   = w * TPW;

    // ---- load this wave's H slice (4 s x 4 t complex = 32 floats) ----
    float Hr[NS][TPW], Hi[NS][TPW];
    const int hbase = b * (NS * NT * SITE) + rem;
    #pragma unroll
    for (int s = 0; s < NS; ++s) {
        #pragma unroll
        for (int tt = 0; tt < TPW; ++tt) {
            const int idx = hbase + (s * NT + t0 + tt) * SITE;
            Hr[s][tt] = hr[idx];
            Hi[s][tt] = hi[idx];
        }
    }
    // ---- load x (4 complex); every wave solves redundantly ----
    float Xr[NS], Xi[NS];
    const int xbase = b * (NS * SITE) + rem;
    #pragma unroll
    for (int s = 0; s < NS; ++s) {
        Xr[s] = xr[xbase + s * SITE];
        Xi[s] = xi[xbase + s * SITE];
    }

    // ---- stage H to LDS (lane-stride 4B: 2 lanes/bank = conflict-free) ----
    #pragma unroll
    for (int s = 0; s < NS; ++s) {
        #pragma unroll
        for (int tt = 0; tt < TPW; ++tt) {
            ldsH[w][s * TPW + tt][0][l] = Hr[s][tt];
            ldsH[w][s * TPW + tt][1][l] = Hi[s][tt];
        }
    }

    // ---- partial A over this wave's 4 t's (Hermitian lower; diag real) ----
    float Ar[NS][NS], Ai[NS][NS];
    #pragma unroll
    for (int i = 0; i < NS; ++i) {
        #pragma unroll
        for (int j = 0; j <= i; ++j) {
            float sr = 0.f, si = 0.f;
            #pragma unroll
            for (int tt = 0; tt < TPW; ++tt) {
                sr += Hr[i][tt] * Hr[j][tt] + Hi[i][tt] * Hi[j][tt];
                si += Hi[i][tt] * Hr[j][tt] - Hr[i][tt] * Hi[j][tt];
            }
            Ar[i][j] = sr;
            Ai[i][j] = si;
        }
    }

    // ---- exchange partials via LDS ----
    {
        float* p = &ldsA[w][0][l];
        p[ 0*64] = Ar[0][0]; p[ 1*64] = Ar[1][1]; p[ 2*64] = Ar[2][2]; p[ 3*64] = Ar[3][3];
        p[ 4*64] = Ar[1][0]; p[ 5*64] = Ai[1][0];
        p[ 6*64] = Ar[2][0]; p[ 7*64] = Ai[2][0];
        p[ 8*64] = Ar[2][1]; p[ 9*64] = Ai[2][1];
        p[10*64] = Ar[3][0]; p[11*64] = Ai[3][0];
        p[12*64] = Ar[3][1]; p[13*64] = Ai[3][1];
        p[14*64] = Ar[3][2]; p[15*64] = Ai[3][2];
    }
    __syncthreads();
    #pragma unroll
    for (int ow = 0; ow < 4; ++ow) {
        if (ow == w) continue;                    // wave-uniform branch
        const float* p = &ldsA[ow][0][l];
        Ar[0][0] += p[ 0*64]; Ar[1][1] += p[ 1*64]; Ar[2][2] += p[ 2*64]; Ar[3][3] += p[ 3*64];
        Ar[1][0] += p[ 4*64]; Ai[1][0] += p[ 5*64];
        Ar[2][0] += p[ 6*64]; Ai[2][0] += p[ 7*64];
        Ar[2][1] += p[ 8*64]; Ai[2][1] += p[ 9*64];
        Ar[3][0] += p[10*64]; Ai[3][0] += p[11*64];
        Ar[3][1] += p[12*64]; Ai[3][1] += p[13*64];
        Ar[3][2] += p[14*64]; Ai[3][2] += p[15*64];
    }

    // ---- complex Cholesky A = L L^H (in-place, 1/diag in invd) ----
    float invd[NS];
    #pragma unroll
    for (int j = 0; j < NS; ++j) {
        float s = Ar[j][j];
        #pragma unroll
        for (int k = 0; k < j; ++k)
            s -= Ar[j][k] * Ar[j][k] + Ai[j][k] * Ai[j][k];
        const float inv = 1.0f / sqrtf(fmaxf(s, 1e-20f));
        invd[j] = inv;
        #pragma unroll
        for (int i = j + 1; i < NS; ++i) {
            float sr = Ar[i][j], si = Ai[i][j];
            #pragma unroll
            for (int k = 0; k < j; ++k) {
                sr -= Ar[i][k] * Ar[j][k] + Ai[i][k] * Ai[j][k];
                si -= Ai[i][k] * Ar[j][k] - Ar[i][k] * Ai[j][k];
            }
            Ar[i][j] = sr * inv;
            Ai[i][j] = si * inv;
        }
    }

    // ---- forward solve L w = x ----
    float Wr[NS], Wi[NS];
    #pragma unroll
    for (int i = 0; i < NS; ++i) {
        float sr = Xr[i], si = Xi[i];
        #pragma unroll
        for (int k = 0; k < i; ++k) {
            sr -= Ar[i][k] * Wr[k] - Ai[i][k] * Wi[k];
            si -= Ar[i][k] * Wi[k] + Ai[i][k] * Wr[k];
        }
        Wr[i] = sr * invd[i];
        Wi[i] = si * invd[i];
    }

    // ---- back solve L^H z = w ----
    float Zr[NS], Zi[NS];
    #pragma unroll
    for (int i = NS - 1; i >= 0; --i) {
        float sr = Wr[i], si = Wi[i];
        #pragma unroll
        for (int k = i + 1; k < NS; ++k) {
            sr -= Ar[k][i] * Zr[k] + Ai[k][i] * Zi[k];
            si -= Ar[k][i] * Zi[k] - Ai[k][i] * Zr[k];
        }
        Zr[i] = sr * invd[i];
        Zi[i] = si * invd[i];
    }

    // ---- y[t] = sum_s conj(H[s][t]) * z[s]; H slice read back from LDS ----
    // Output complex array is (B,1,T,OFDM,FFT); site idx = b*(NT*SITE) + t*SITE + rem.
    const int obase = b * (NT * SITE) + rem;
    #pragma unroll
    for (int tt = 0; tt < TPW; ++tt) {
        float yr = 0.f, yi = 0.f;
        #pragma unroll
        for (int s = 0; s < NS; ++s) {
            const float hrv = ldsH[w][s * TPW + tt][0][l];
            const float hiv = ldsH[w][s * TPW + tt][1][l];
            yr += hrv * Zr[s] + hiv * Zi[s];
            if (MODE == 1) yi += hrv * Zi[s] - hiv * Zr[s];
        }
        const int o = obase + (t0 + tt) * SITE;
        if (MODE == 0) {
            ((float*)out_raw)[o] = yr;           // harness compares Re(y) only
        } else {
            ((unsigned int*)out_raw)[o] =
                (unsigned int)bf16_bits(yr) | ((unsigned int)bf16_bits(yi) << 16);
        }
    }
}

extern "C" void kernel_launch(void* const* d_in, const int* in_sizes, int n_in,
                              void* d_out, int out_size, void* d_ws, size_t ws_size,
                              hipStream_t stream) {
    // Inputs in setup_inputs() dict order:
    //   [0]=x_real, [1]=x_imag, [2]=h_real, [3]=h_imag, [4]=precoding_ind
    const float* xr = (const float*)d_in[0];
    const float* xi = (const float*)d_in[1];
    const float* hr = (const float*)d_in[2];
    const float* hi = (const float*)d_in[3];

    const int grid = NSITES / 64;   // 3584 blocks x 256 threads (4 waves x 64 sites)
    if (out_size == NB * NT * SITE) {
        // complex64 ref stored as float32 (imag dropped): write Re(y) only.
        zf_precoder_kernel<0><<<grid, 256, 0, stream>>>(xr, xi, hr, hi, d_out);
    } else {
        // fallback: bf16 interleaved (re,im)
        zf_precoder_kernel<1><<<grid, 256, 0, stream>>>(xr, xi, hr, hi, d_out);
    }
}

// Round 13
// 27.280 us; speedup vs baseline: 1.0558x; 1.0558x over previous
//
#include <hip/hip_runtime.h>
#include <hip/hip_bf16.h>

// Problem constants: B=16, NTX=1, S=4, OFDM=14, FFT=1024, NRX=4, NRXA=1, T=16.
// precoding_ind = arange(4) -> identity selection (folded into indexing).
#define NB    16
#define NS    4
#define NT    16
#define NOFDM 14
#define NFFT  1024
#define SITE  (NOFDM * NFFT)          // 14336 sites per b (divisible by 128: no b-straddle)
#define NSITES (NB * SITE)            // 229376 sites total
#define TPW   4                       // t's per wave (NT / 4 waves)
#define SPT   2                       // consecutive sites per thread -> float2 global access

// RNE float -> bf16 bits (fallback path only)
__device__ __forceinline__ unsigned short bf16_bits(float f) {
    unsigned int u = __float_as_uint(f);
    return (unsigned short)((u + 0x7FFFu + ((u >> 16) & 1u)) >> 16);
}

template <int MODE>   // 0: f32 real-part only (out_size=3670016); 1: bf16 interleaved pairs
__global__ __launch_bounds__(256, 2)   // VGPR cap 256: ~180 needed for 2-site state
void zf_precoder_kernel(
    const float* __restrict__ xr, const float* __restrict__ xi,
    const float* __restrict__ hr, const float* __restrict__ hi,
    void* __restrict__ out_raw)
{
    // Partial-A exchange: [wave][fi][site-in-block], float2 per thread = 32 KB
    __shared__ float ldsA[4][16][64 * SPT];

    const int tid   = threadIdx.x;
    const int w     = tid >> 6;                   // wave 0..3 -> t range [4w, 4w+4)
    const int l     = tid & 63;                   // lane
    const int site0 = blockIdx.x * (64 * SPT) + l * SPT;   // even; +1 = same b
    const int b     = site0 / SITE;
    const int rem   = site0 - b * SITE;
    const int t0    = w * TPW;

    // ---- load this wave's H slice for BOTH sites as float2 (512 B/wave-instr) ----
    float Hr[NS][TPW][SPT], Hi[NS][TPW][SPT];
    const int hbase = b * (NS * NT * SITE) + rem;
    #pragma unroll
    for (int s = 0; s < NS; ++s) {
        #pragma unroll
        for (int tt = 0; tt < TPW; ++tt) {
            const int idx = hbase + (s * NT + t0 + tt) * SITE;
            const float2 vr = *(const float2*)&hr[idx];
            const float2 vi = *(const float2*)&hi[idx];
            Hr[s][tt][0] = vr.x; Hr[s][tt][1] = vr.y;
            Hi[s][tt][0] = vi.x; Hi[s][tt][1] = vi.y;
        }
    }
    // ---- load x for both sites (each wave redundantly; L2-hit after wave 0) ----
    float Xr[NS][SPT], Xi[NS][SPT];
    const int xbase = b * (NS * SITE) + rem;
    #pragma unroll
    for (int s = 0; s < NS; ++s) {
        const float2 vr = *(const float2*)&xr[xbase + s * SITE];
        const float2 vi = *(const float2*)&xi[xbase + s * SITE];
        Xr[s][0] = vr.x; Xr[s][1] = vr.y;
        Xi[s][0] = vi.x; Xi[s][1] = vi.y;
    }

    // ---- partial A over this wave's 4 t's, per site (Hermitian lower) ----
    float Ar[NS][NS][SPT], Ai[NS][NS][SPT];
    #pragma unroll
    for (int i = 0; i < NS; ++i) {
        #pragma unroll
        for (int j = 0; j <= i; ++j) {
            #pragma unroll
            for (int p = 0; p < SPT; ++p) {
                float sr = 0.f, si = 0.f;
                #pragma unroll
                for (int tt = 0; tt < TPW; ++tt) {
                    sr += Hr[i][tt][p] * Hr[j][tt][p] + Hi[i][tt][p] * Hi[j][tt][p];
                    si += Hi[i][tt][p] * Hr[j][tt][p] - Hr[i][tt][p] * Hi[j][tt][p];
                }
                Ar[i][j][p] = sr;
                Ai[i][j][p] = si;
            }
        }
    }

    // ---- exchange partials via LDS (float2 per thread per fi) ----
    {
        const int c = l * SPT;
        #define WR2(fi, a) *(float2*)&ldsA[w][fi][c] = make_float2((a)[0], (a)[1])
        WR2( 0, Ar[0][0]); WR2( 1, Ar[1][1]); WR2( 2, Ar[2][2]); WR2( 3, Ar[3][3]);
        WR2( 4, Ar[1][0]); WR2( 5, Ai[1][0]);
        WR2( 6, Ar[2][0]); WR2( 7, Ai[2][0]);
        WR2( 8, Ar[2][1]); WR2( 9, Ai[2][1]);
        WR2(10, Ar[3][0]); WR2(11, Ai[3][0]);
        WR2(12, Ar[3][1]); WR2(13, Ai[3][1]);
        WR2(14, Ar[3][2]); WR2(15, Ai[3][2]);
        #undef WR2
    }
    __syncthreads();
    #pragma unroll
    for (int ow = 0; ow < 4; ++ow) {
        if (ow == w) continue;                    // wave-uniform branch
        const int c = l * SPT;
        #define RD2(fi, a) { float2 v = *(const float2*)&ldsA[ow][fi][c]; (a)[0] += v.x; (a)[1] += v.y; }
        RD2( 0, Ar[0][0]); RD2( 1, Ar[1][1]); RD2( 2, Ar[2][2]); RD2( 3, Ar[3][3]);
        RD2( 4, Ar[1][0]); RD2( 5, Ai[1][0]);
        RD2( 6, Ar[2][0]); RD2( 7, Ai[2][0]);
        RD2( 8, Ar[2][1]); RD2( 9, Ai[2][1]);
        RD2(10, Ar[3][0]); RD2(11, Ai[3][0]);
        RD2(12, Ar[3][1]); RD2(13, Ai[3][1]);
        RD2(14, Ar[3][2]); RD2(15, Ai[3][2]);
        #undef RD2
    }

    // ---- per-site complex Cholesky + solves (p-unrolled: independent ILP) ----
    float Zr[NS][SPT], Zi[NS][SPT];
    #pragma unroll
    for (int p = 0; p < SPT; ++p) {
        float invd[NS];
        #pragma unroll
        for (int j = 0; j < NS; ++j) {
            float s = Ar[j][j][p];
            #pragma unroll
            for (int k = 0; k < j; ++k)
                s -= Ar[j][k][p] * Ar[j][k][p] + Ai[j][k][p] * Ai[j][k][p];
            const float inv = 1.0f / sqrtf(fmaxf(s, 1e-20f));
            invd[j] = inv;
            #pragma unroll
            for (int i = j + 1; i < NS; ++i) {
                float sr = Ar[i][j][p], si = Ai[i][j][p];
                #pragma unroll
                for (int k = 0; k < j; ++k) {
                    sr -= Ar[i][k][p] * Ar[j][k][p] + Ai[i][k][p] * Ai[j][k][p];
                    si -= Ai[i][k][p] * Ar[j][k][p] - Ar[i][k][p] * Ai[j][k][p];
                }
                Ar[i][j][p] = sr * inv;
                Ai[i][j][p] = si * inv;
            }
        }
        float Wr[NS], Wi[NS];
        #pragma unroll
        for (int i = 0; i < NS; ++i) {
            float sr = Xr[i][p], si = Xi[i][p];
            #pragma unroll
            for (int k = 0; k < i; ++k) {
                sr -= Ar[i][k][p] * Wr[k] - Ai[i][k][p] * Wi[k];
                si -= Ar[i][k][p] * Wi[k] + Ai[i][k][p] * Wr[k];
            }
            Wr[i] = sr * invd[i];
            Wi[i] = si * invd[i];
        }
        #pragma unroll
        for (int i = NS - 1; i >= 0; --i) {
            float sr = Wr[i], si = Wi[i];
            #pragma unroll
            for (int k = i + 1; k < NS; ++k) {
                sr -= Ar[k][i][p] * Zr[k][p] + Ai[k][i][p] * Zi[k][p];
                si -= Ar[k][i][p] * Zi[k][p] - Ai[k][i][p] * Zr[k][p];
            }
            Zr[i][p] = sr * invd[i];
            Zi[i][p] = si * invd[i];
        }
    }

    // ---- y[t] = sum_s conj(H[s][t]) * z[s]; float2 stores (both sites) ----
    // Output complex array is (B,1,T,OFDM,FFT); site idx = b*(NT*SITE) + t*SITE + rem.
    const int obase = b * (NT * SITE) + rem;
    #pragma unroll
    for (int tt = 0; tt < TPW; ++tt) {
        float yr[SPT], yi[SPT];
        #pragma unroll
        for (int p = 0; p < SPT; ++p) {
            float ar = 0.f, ai = 0.f;
            #pragma unroll
            for (int s = 0; s < NS; ++s) {
                ar += Hr[s][tt][p] * Zr[s][p] + Hi[s][tt][p] * Zi[s][p];
                ai += Hr[s][tt][p] * Zi[s][p] - Hi[s][tt][p] * Zr[s][p];
            }
            yr[p] = ar; yi[p] = ai;
        }
        const int o = obase + (t0 + tt) * SITE;
        if (MODE == 0) {
            *(float2*)&((float*)out_raw)[o] = make_float2(yr[0], yr[1]);
        } else {
            uint2 v;
            v.x = (unsigned int)bf16_bits(yr[0]) | ((unsigned int)bf16_bits(yi[0]) << 16);
            v.y = (unsigned int)bf16_bits(yr[1]) | ((unsigned int)bf16_bits(yi[1]) << 16);
            *(uint2*)&((unsigned int*)out_raw)[o] = v;
        }
    }
}

extern "C" void kernel_launch(void* const* d_in, const int* in_sizes, int n_in,
                              void* d_out, int out_size, void* d_ws, size_t ws_size,
                              hipStream_t stream) {
    // Inputs in setup_inputs() dict order:
    //   [0]=x_real, [1]=x_imag, [2]=h_real, [3]=h_imag, [4]=precoding_ind
    const float* xr = (const float*)d_in[0];
    const float* xi = (const float*)d_in[1];
    const float* hr = (const float*)d_in[2];
    const float* hi = (const float*)d_in[3];

    const int grid = NSITES / (64 * SPT);   // 1792 blocks x 256 threads (4 waves x 128 sites)
    if (out_size == NB * NT * SITE) {
        // complex64 ref stored as float32 (imag dropped): write Re(y) only.
        zf_precoder_kernel<0><<<grid, 256, 0, stream>>>(xr, xi, hr, hi, d_out);
    } else {
        // fallback: bf16 interleaved (re,im)
        zf_precoder_kernel<1><<<grid, 256, 0, stream>>>(xr, xi, hr, hi, d_out);
    }
}